// Round 2
// baseline (366.360 us; speedup 1.0000x reference)
//
#include <hip/hip_runtime.h>

#define BB 128
#define TT 512
#define CC 128

// ---------------------------------------------------------------------------
// Kernel 1: real path score = emission + transition, accumulated NEGATED into
// out[b] via atomicAdd (out zeroed beforehand by hipMemsetAsync).
// Grid: (B, 8) blocks x 256 threads; each wave handles 16 consecutive t's
// (+1 overlap row). Row t+1 is prefetched into registers while row t is
// processed so HBM latency doesn't serialize the 17-row loop.
// ---------------------------------------------------------------------------
__global__ __launch_bounds__(256) void crf_real_path(
    const float* __restrict__ y_true, const float* __restrict__ y_pred,
    const float* __restrict__ mask, const float* __restrict__ trans,
    float* __restrict__ out)
{
    const int b    = blockIdx.x;
    const int tid  = threadIdx.x;
    const int lane = tid & 63;
    const int w    = tid >> 6;
    const int seg  = blockIdx.y * 4 + w;   // 0..31
    const int ts   = seg * 16;
    const int te   = min(ts + 16, TT - 1); // inclusive overlap row

    const float* yt_b = y_true + (size_t)b * TT * CC;
    const float* yp_b = y_pred + (size_t)b * TT * CC;
    const float* m_b  = mask + (size_t)b * TT;

    float em = 0.f, tr = 0.f;
    int lprev = 0; float mprev = 0.f;

    const float* ytr = yt_b + ts * CC;
    const float* ypr = yp_b + ts * CC;
    float cyt0 = ytr[lane], cyt1 = ytr[lane + 64];
    float cyp0 = ypr[lane], cyp1 = ypr[lane + 64];
    float cm = m_b[ts];

    for (int t = ts; t <= te; ++t) {
        float nyt0 = 0.f, nyt1 = 0.f, nyp0 = 0.f, nyp1 = 0.f, nm = 0.f;
        if (t < te) {                       // prefetch next row first
            const float* ytn = yt_b + (t + 1) * CC;
            const float* ypn = yp_b + (t + 1) * CC;
            nyt0 = ytn[lane]; nyt1 = ytn[lane + 64];
            nyp0 = ypn[lane]; nyp1 = ypn[lane + 64];
            nm = m_b[t + 1];
        }
        unsigned long long b0 = __ballot(cyt0 > 0.5f);
        unsigned long long b1 = __ballot(cyt1 > 0.5f);
        int l = b0 ? (__ffsll(b0) - 1) : (64 + __ffsll(b1) - 1);
        float v0 = __shfl(cyp0, l & 63);
        float v1 = __shfl(cyp1, l & 63);
        float v  = (l < 64) ? v0 : v1;
        if (lane == 0) {
            if (t < ts + 16) em += cm * cm * v;                 // emission (masked^2)
            if (t > ts)      tr += mprev * cm * trans[lprev * CC + l];
        }
        lprev = l; mprev = cm;
        cyt0 = nyt0; cyt1 = nyt1; cyp0 = nyp0; cyp1 = nyp1; cm = nm;
    }
    if (lane == 0) atomicAdd(&out[b], -(em + tr));
}

// ---------------------------------------------------------------------------
// Kernel 2: forward scan in LINEAR space, TWO batches per 1024-thread block
// (independent recurrences overlap each other's latencies; 4 waves/SIMD).
// Per half: thread (j = lt>>2, c4 = lt&3) owns E[i][j] for i in c4*32..+32
// in 32 fp32 registers. State (128 floats) double-buffered in LDS with an
// XOR-rotate bank swizzle (verified conflict-free in R1). One barrier/step.
// Renorm every 4 steps by 1/state[0] (no reduction needed: all entries are
// within 2^17.3 of each other, growth <= 2^15.7/step -> worst-case < 2^80,
// no overflow). Scale applied lazily at the next state write.
// ---------------------------------------------------------------------------
__global__ __launch_bounds__(1024) void crf_forward(
    const float* __restrict__ y_pred, const float* __restrict__ mask,
    const float* __restrict__ trans, float* __restrict__ out)
{
    __shared__ __align__(16) float pbuf[2][2 * CC];  // [half][parity*CC + slot]

    const int tid  = threadIdx.x;
    const int half = tid >> 9;
    const int lt   = tid & 511;
    const int b    = blockIdx.x * 2 + half;
    const int j    = lt >> 2;   // 0..127 output column
    const int c4   = lt & 3;    // i-chunk

    float* P = pbuf[half];

    // E = exp(trans) in registers
    float Ereg[32];
    #pragma unroll
    for (int k = 0; k < 32; ++k)
        Ereg[k] = __expf(trans[(c4 * 32 + k) * CC + j]);

    const float* yp_b = y_pred + (size_t)b * TT * CC;
    const float* m_b  = mask + (size_t)b * TT;

    // Bank swizzle (same as R1: zero conflicts measured)
    const float4* pp[8];
    #pragma unroll
    for (int k = 0; k < 8; ++k) {
        int pc = c4 * 8 + ((k + 2 * c4) & 7);
        pp[k] = (const float4*)P + pc;
    }
    int pj = (j & ~31) | ((j + 8 * (j >> 5)) & 31);  // physical slot for col j
    float* wptr = P + pj;
    // note: logical column 0 -> physical slot 0 (renorm reads P[wq*CC + 0])

    if (c4 == 0) wptr[0] = __expf(yp_b[j] * m_b[0]);
    __syncthreads();

    // depth-4 prefetch of x_t rows and mask
    float xpre[4], mpre[4];
    #pragma unroll
    for (int k = 0; k < 4; ++k) {
        int tt = min(1 + k, TT - 1);
        xpre[k] = yp_b[tt * CC + j];
        mpre[k] = m_b[tt];
    }

    float pending = 1.0f;
    float log_acc = 0.0f;

    for (int g = 0; g < 128; ++g) {
        #pragma unroll
        for (int k = 0; k < 4; ++k) {
            const int t = 4 * g + k + 1;
            if (t < TT) {                       // block-uniform guard
                const int rq = k & 1;           // read parity
                const int wq = rq ^ 1;          // write parity
                float xv = xpre[k];
                float mv = mpre[k];
                int tp = min(t + 4, TT - 1);
                xpre[k] = yp_b[tp * CC + j];
                mpre[k] = m_b[tp];

                // 4 accumulators: dependent-FMA chain depth 8, not 32
                float d0 = 0.f, d1 = 0.f, d2 = 0.f, d3 = 0.f;
                #pragma unroll
                for (int kk = 0; kk < 8; kk += 4) {
                    float4 p0 = *(pp[kk + 0] + rq * 32);
                    float4 p1 = *(pp[kk + 1] + rq * 32);
                    float4 p2 = *(pp[kk + 2] + rq * 32);
                    float4 p3 = *(pp[kk + 3] + rq * 32);
                    d0 = fmaf(p0.x, Ereg[4 * kk + 0], d0);
                    d0 = fmaf(p0.y, Ereg[4 * kk + 1], d0);
                    d1 = fmaf(p0.z, Ereg[4 * kk + 2], d1);
                    d1 = fmaf(p0.w, Ereg[4 * kk + 3], d1);
                    d0 = fmaf(p1.x, Ereg[4 * kk + 4], d0);
                    d0 = fmaf(p1.y, Ereg[4 * kk + 5], d0);
                    d1 = fmaf(p1.z, Ereg[4 * kk + 6], d1);
                    d1 = fmaf(p1.w, Ereg[4 * kk + 7], d1);
                    d2 = fmaf(p2.x, Ereg[4 * kk + 8], d2);
                    d2 = fmaf(p2.y, Ereg[4 * kk + 9], d2);
                    d3 = fmaf(p2.z, Ereg[4 * kk + 10], d3);
                    d3 = fmaf(p2.w, Ereg[4 * kk + 11], d3);
                    d2 = fmaf(p3.x, Ereg[4 * kk + 12], d2);
                    d2 = fmaf(p3.y, Ereg[4 * kk + 13], d2);
                    d3 = fmaf(p3.z, Ereg[4 * kk + 14], d3);
                    d3 = fmaf(p3.w, Ereg[4 * kk + 15], d3);
                }
                float dot = (d0 + d1) + (d2 + d3);
                dot += __shfl_xor(dot, 1);
                dot += __shfl_xor(dot, 2);

                if (c4 == 0) {
                    float val = (mv > 0.f) ? dot * __expf(xv) : wptr[rq * CC];
                    wptr[wq * CC] = val * pending;
                }
                pending = 1.0f;
                __syncthreads();

                if (k == 3) {
                    // renorm by state[0] (broadcast LDS read, no reduction,
                    // no extra barriers). wq == 0 here always (t % 4 == 0).
                    float v = P[wq * CC + 0];
                    pending = 1.0f / v;
                    log_acc += __logf(v);
                }
            }
        }
    }

    // last write was t=511 -> parity 1. Sum is swizzle-invariant.
    if (lt < 64) {
        float sm = P[CC + lt] + P[CC + lt + 64];
        #pragma unroll
        for (int s = 32; s >= 1; s >>= 1)
            sm += __shfl_xor(sm, s);
        if (lt == 0)
            out[b] = __logf(sm) + log_acc + out[b];   // out[b] holds -real_path
    }
}

// ---------------------------------------------------------------------------
extern "C" void kernel_launch(void* const* d_in, const int* in_sizes, int n_in,
                              void* d_out, int out_size, void* d_ws, size_t ws_size,
                              hipStream_t stream) {
    (void)in_sizes; (void)n_in; (void)out_size; (void)d_ws; (void)ws_size;
    const float* y_true = (const float*)d_in[0];
    const float* y_pred = (const float*)d_in[1];
    const float* mask   = (const float*)d_in[2];
    const float* trans  = (const float*)d_in[3];
    float* out = (float*)d_out;

    hipMemsetAsync(out, 0, BB * sizeof(float), stream);
    crf_real_path<<<dim3(BB, 8), 256, 0, stream>>>(y_true, y_pred, mask, trans, out);
    crf_forward<<<dim3(BB / 2), 1024, 0, stream>>>(y_pred, mask, trans, out);
}

// Round 3
// 334.000 us; speedup vs baseline: 1.0969x; 1.0969x over previous
//
#include <hip/hip_runtime.h>

#define BB 128
#define TT 512
#define CC 128
#define G  16        // batches per forward block
#define NFWD 8       // forward blocks (8 x 16 = 128 batches)
#define RS 136       // padded LDS row stride in bf16 (272B: 16B-aligned, uniform banks)
#define PSTR (G*RS)  // shorts per parity buffer (2176)

typedef short short8 __attribute__((ext_vector_type(8)));
typedef float f32x4  __attribute__((ext_vector_type(4)));

__device__ __forceinline__ unsigned short f32_to_bf16(float f) {
    union { float f; unsigned int u; } v; v.f = f;
    unsigned int r = v.u + 0x7FFFu + ((v.u >> 16) & 1u);   // RNE
    return (unsigned short)(r >> 16);
}
__device__ __forceinline__ float bf16_to_f32(unsigned short h) {
    union { unsigned int u; float f; } v; v.u = ((unsigned int)h) << 16;
    return v.f;
}

// ---------------------------------------------------------------------------
// Fused kernel. Blocks 0..7: MFMA forward scan (16 batches each).
// Blocks 8..135: real-path score (one batch each), atomicAdd(-score) into out.
// out is zeroed by hipMemsetAsync; forward blocks atomicAdd(+all_paths).
// ---------------------------------------------------------------------------
__global__ __launch_bounds__(512) void crf_fused(
    const float* __restrict__ y_true, const float* __restrict__ y_pred,
    const float* __restrict__ mask, const float* __restrict__ trans,
    float* __restrict__ out)
{
    __shared__ __align__(16) unsigned short Sb[2 * PSTR];  // double-buffered state, bf16
    __shared__ float rsum[8];

    const int tid  = threadIdx.x;
    const int lane = tid & 63;
    const int w    = tid >> 6;

    if (blockIdx.x >= NFWD) {
        // ================= real path: emission + transition =================
        const int rb = blockIdx.x - NFWD;
        const float* yt_b = y_true + (size_t)rb * TT * CC;
        const float* yp_b = y_pred + (size_t)rb * TT * CC;
        const float* m_b  = mask + (size_t)rb * TT;
        const int ts = w * 64;
        const int te = min(ts + 64, TT - 1);   // +1 overlap row for boundary pair

        float em = 0.f, tr = 0.f;
        int lprev = 0; float mprev = 0.f;

        const float* ytr = yt_b + ts * CC;
        const float* ypr = yp_b + ts * CC;
        float cyt0 = ytr[lane], cyt1 = ytr[lane + 64];
        float cyp0 = ypr[lane], cyp1 = ypr[lane + 64];
        float cm = m_b[ts];

        for (int t = ts; t <= te; ++t) {
            float nyt0 = 0.f, nyt1 = 0.f, nyp0 = 0.f, nyp1 = 0.f, nm = 0.f;
            if (t < te) {                      // prefetch next row
                const float* ytn = yt_b + (t + 1) * CC;
                const float* ypn = yp_b + (t + 1) * CC;
                nyt0 = ytn[lane]; nyt1 = ytn[lane + 64];
                nyp0 = ypn[lane]; nyp1 = ypn[lane + 64];
                nm = m_b[t + 1];
            }
            unsigned long long b0 = __ballot(cyt0 > 0.5f);
            unsigned long long b1 = __ballot(cyt1 > 0.5f);
            int l = b0 ? (__ffsll(b0) - 1) : (64 + __ffsll(b1) - 1);
            float v0 = __shfl(cyp0, l & 63);
            float v1 = __shfl(cyp1, l & 63);
            float v  = (l < 64) ? v0 : v1;
            if (lane == 0) {
                if (t < ts + 64) em += cm * cm * v;
                if (t > ts)      tr += mprev * cm * trans[lprev * CC + l];
            }
            lprev = l; mprev = cm;
            cyt0 = nyt0; cyt1 = nyt1; cyp0 = nyp0; cyp1 = nyp1; cm = nm;
        }
        if (lane == 0) rsum[w] = em + tr;
        __syncthreads();
        if (tid == 0) {
            float s = 0.f;
            #pragma unroll
            for (int i = 0; i < 8; ++i) s += rsum[i];
            atomicAdd(&out[rb], -s);
        }
        return;
    }

    // ====================== MFMA forward scan ======================
    // Wave w owns N-tile (cols 16w..16w+15). MFMA 16x16x32_bf16:
    //  A[m][k]: m = lane&15 (local batch), k = quad*8+e  -> b128 from LDS
    //  B[k][n]: n = lane&15 (col within tile), k = quad*8+e -> regs (E=exp(trans))
    //  D[m][n]: m = quad*4+reg, n = lane&15               (m89-verified C layout)
    const int bg0  = blockIdx.x * G;
    const int n    = lane & 15;
    const int q    = lane >> 4;
    const int jcol = w * 16 + n;

    // B fragments: E = exp(trans) for this wave's 16 columns, all 4 K-tiles.
    short8 Bf[4];
    #pragma unroll
    for (int kt = 0; kt < 4; ++kt) {
        #pragma unroll
        for (int e = 0; e < 8; ++e) {
            int i = kt * 32 + q * 8 + e;
            Bf[kt][e] = (short)f32_to_bf16(__expf(trans[i * CC + jcol]));
        }
    }

    // per-lane global bases: D-lane (q,r) holds local batch q*4+r
    const float* xbase[4]; const float* mbase[4];
    int wrow[4];            // LDS offset (shorts) of (row=q*4+r, col=jcol)
    int srow[4];            // LDS offset of (row=q*4+r, col=0) for renorm scale
    #pragma unroll
    for (int r = 0; r < 4; ++r) {
        int lb = q * 4 + r;
        xbase[r] = y_pred + (size_t)(bg0 + lb) * TT * CC + jcol;
        mbase[r] = mask + (size_t)(bg0 + lb) * TT;
        wrow[r] = lb * RS + jcol;
        srow[r] = lb * RS;
    }
    const unsigned short* Ab = &Sb[n * RS + q * 8];   // A-frag base (row = n!)

    float pend[4] = {1.f, 1.f, 1.f, 1.f};
    float lacc[4] = {0.f, 0.f, 0.f, 0.f};

    // t=0 init: S0 = exp(y_pred[:,0] * mask[:,0])  -> parity 0
    #pragma unroll
    for (int r = 0; r < 4; ++r)
        Sb[wrow[r]] = f32_to_bf16(__expf(xbase[r][0] * mbase[r][0]));
    __syncthreads();

    // depth-2 prefetch ring: slot = t&1
    float xp[2][4], mp[2][4];
    #pragma unroll
    for (int r = 0; r < 4; ++r) {
        xp[1][r] = xbase[r][1 * CC]; mp[1][r] = mbase[r][1];
        xp[0][r] = xbase[r][2 * CC]; mp[0][r] = mbase[r][2];
    }

    auto step = [&](int t, int rp, int wp) {
        const unsigned short* A = Ab + rp * PSTR;
        short8 a0 = *(const short8*)(A +  0);
        short8 a1 = *(const short8*)(A + 32);
        short8 a2 = *(const short8*)(A + 64);
        short8 a3 = *(const short8*)(A + 96);
        f32x4 acc = {0.f, 0.f, 0.f, 0.f};
        acc = __builtin_amdgcn_mfma_f32_16x16x32_bf16(a0, Bf[0], acc, 0, 0, 0);
        acc = __builtin_amdgcn_mfma_f32_16x16x32_bf16(a1, Bf[1], acc, 0, 0, 0);
        acc = __builtin_amdgcn_mfma_f32_16x16x32_bf16(a2, Bf[2], acc, 0, 0, 0);
        acc = __builtin_amdgcn_mfma_f32_16x16x32_bf16(a3, Bf[3], acc, 0, 0, 0);

        const int sl = t & 1;
        float xv[4], mv[4];
        #pragma unroll
        for (int r = 0; r < 4; ++r) { xv[r] = xp[sl][r]; mv[r] = mp[sl][r]; }
        int tp = t + 2; if (tp > TT - 1) tp = TT - 1;      // harmless refetch
        #pragma unroll
        for (int r = 0; r < 4; ++r) {
            xp[sl][r] = xbase[r][tp * CC]; mp[sl][r] = mbase[r][tp];
        }

        float val[4];
        #pragma unroll
        for (int r = 0; r < 4; ++r)
            val[r] = acc[r] * __expf(xv[r] * mv[r]);
        // mask==0 -> keep old state (never taken in this benchmark; wave-uniform)
        if (__ballot(mv[0] <= 0.f || mv[1] <= 0.f || mv[2] <= 0.f || mv[3] <= 0.f)) {
            #pragma unroll
            for (int r = 0; r < 4; ++r)
                if (mv[r] <= 0.f) val[r] = bf16_to_f32(Sb[rp * PSTR + wrow[r]]);
        }
        #pragma unroll
        for (int r = 0; r < 4; ++r) {
            Sb[wp * PSTR + wrow[r]] = f32_to_bf16(val[r] * pend[r]);
            pend[r] = 1.f;
        }
        __syncthreads();
    };

    auto renorm = [&](int wp) {   // per-batch scale by S[b][0]; exact (1/s, log s) pair
        #pragma unroll
        for (int r = 0; r < 4; ++r) {
            float s = bf16_to_f32(Sb[wp * PSTR + srow[r]]);
            pend[r] = __builtin_amdgcn_rcpf(s);
            lacc[r] += __logf(s);
        }
    };

    for (int tb = 1; tb < TT; tb += 2) {
        step(tb, 0, 1);                        // t odd:  read p0, write p1
        if (tb + 1 < TT) {
            step(tb + 1, 1, 0);                // t even: read p1, write p0
            if (((tb + 1) & 3) == 0) renorm(0);
        }
    }

    // final state S_511 at parity 1: all_paths[b] = log(sum_j S[b][j]) + lacc[b]
    #pragma unroll
    for (int u = 0; u < 2; ++u) {
        int lb = w * 2 + u;
        float sm = bf16_to_f32(Sb[PSTR + lb * RS + lane])
                 + bf16_to_f32(Sb[PSTR + lb * RS + 64 + lane]);
        #pragma unroll
        for (int s = 32; s >= 1; s >>= 1) sm += __shfl_xor(sm, s);
        if (lane == (lb >> 2) * 16)            // this lane's lacc[lb&3] is batch lb
            atomicAdd(&out[bg0 + lb], __logf(sm) + lacc[lb & 3]);
    }
}

// ---------------------------------------------------------------------------
extern "C" void kernel_launch(void* const* d_in, const int* in_sizes, int n_in,
                              void* d_out, int out_size, void* d_ws, size_t ws_size,
                              hipStream_t stream) {
    (void)in_sizes; (void)n_in; (void)out_size; (void)d_ws; (void)ws_size;
    const float* y_true = (const float*)d_in[0];
    const float* y_pred = (const float*)d_in[1];
    const float* mask   = (const float*)d_in[2];
    const float* trans  = (const float*)d_in[3];
    float* out = (float*)d_out;

    hipMemsetAsync(out, 0, BB * sizeof(float), stream);
    crf_fused<<<dim3(NFWD + BB), 512, 0, stream>>>(y_true, y_pred, mask, trans, out);
}

// Round 4
// 328.830 us; speedup vs baseline: 1.1141x; 1.0157x over previous
//
#include <hip/hip_runtime.h>

#define BB 128
#define TT 512
#define CC 128

typedef short short8 __attribute__((ext_vector_type(8)));
typedef float f32x4  __attribute__((ext_vector_type(4)));

__device__ __forceinline__ unsigned pkbf16(float a, float b) {
    // positive-only round-half-up bf16 pack: lo16 = bf16(a), hi16 = bf16(b)
    unsigned ua = __float_as_uint(a) + 0x8000u;
    unsigned ub = __float_as_uint(b) + 0x8000u;
    return __builtin_amdgcn_perm(ua, ub, 0x03020706u);
}
__device__ __forceinline__ unsigned short f2bf(float f) {
    unsigned u = __float_as_uint(f);
    u += 0x7fffu + ((u >> 16) & 1u);
    return (unsigned short)(u >> 16);
}
__device__ __forceinline__ float lo16f(unsigned u) { return __uint_as_float(u << 16); }
__device__ __forceinline__ float hi16f(unsigned u) { return __uint_as_float(u & 0xffff0000u); }

// ---------------------------------------------------------------------------
// Prep: ws[id] = exp(y_pred * mask) gathered into the scan's B-layout order.
// id = ((g*512 + t)*8 + c)*64 + lane ; float4 per thread.
// chunk c -> (kt = c>>1, h = c&1); elems u=0..3 -> j = kt*32 + q*8 + 4h + u.
// ---------------------------------------------------------------------------
__global__ __launch_bounds__(256) void crf_prep(
    const float* __restrict__ yp, const float* __restrict__ mask,
    float4* __restrict__ ws)
{
    const int id   = blockIdx.x * 256 + threadIdx.x;
    const int lane = id & 63;
    const int c    = (id >> 6) & 7;
    const int t    = (id >> 9) & 511;
    const int g    = id >> 18;
    const int b    = g * 16 + (lane & 15);
    const int q    = (lane >> 4);
    const int j0   = ((c >> 1) * 32) + q * 8 + ((c & 1) * 4);
    const float4 v = *(const float4*)(yp + ((size_t)b * TT + t) * CC + j0);
    const float m  = mask[b * TT + t];
    float4 r;
    r.x = __expf(v.x * m); r.y = __expf(v.y * m);
    r.z = __expf(v.z * m); r.w = __expf(v.w * m);
    ws[id] = r;
}

// ---------------------------------------------------------------------------
// Fused: blocks 0..7 = barrier-free in-register MFMA scan (16 batches/wave);
// blocks 8..1031 = real-path score waves (8 per batch), atomicAdd(-score).
// ---------------------------------------------------------------------------
template<bool USE_WS>
__global__ __launch_bounds__(64) void crf_fused(
    const float* __restrict__ y_true, const float* __restrict__ y_pred,
    const float* __restrict__ mask, const float* __restrict__ trans,
    const float4* __restrict__ ws, float* __restrict__ out)
{
    const int lane = threadIdx.x;

    if (blockIdx.x >= 8) {
        // ===================== real path (R3-verified logic) ================
        const int rbw = blockIdx.x - 8;
        const int rb  = rbw >> 3;
        const int w   = rbw & 7;
        const int ts  = w * 64;
        const int te  = min(ts + 64, TT - 1);
        const float* yt_b = y_true + (size_t)rb * TT * CC;
        const float* yp_b = y_pred + (size_t)rb * TT * CC;
        const float* m_b  = mask + (size_t)rb * TT;

        float em = 0.f, tr = 0.f;
        int lprev = 0; float mprev = 0.f;
        const float* ytr = yt_b + ts * CC;
        const float* ypr = yp_b + ts * CC;
        float cyt0 = ytr[lane], cyt1 = ytr[lane + 64];
        float cyp0 = ypr[lane], cyp1 = ypr[lane + 64];
        float cm = m_b[ts];
        for (int t = ts; t <= te; ++t) {
            float nyt0 = 0.f, nyt1 = 0.f, nyp0 = 0.f, nyp1 = 0.f, nm = 0.f;
            if (t < te) {
                const float* ytn = yt_b + (t + 1) * CC;
                const float* ypn = yp_b + (t + 1) * CC;
                nyt0 = ytn[lane]; nyt1 = ytn[lane + 64];
                nyp0 = ypn[lane]; nyp1 = ypn[lane + 64];
                nm = m_b[t + 1];
            }
            unsigned long long b0 = __ballot(cyt0 > 0.5f);
            unsigned long long b1 = __ballot(cyt1 > 0.5f);
            int l = b0 ? (__ffsll(b0) - 1) : (64 + __ffsll(b1) - 1);
            float v0 = __shfl(cyp0, l & 63);
            float v1 = __shfl(cyp1, l & 63);
            float v  = (l < 64) ? v0 : v1;
            if (lane == 0) {
                if (t < ts + 64) em += cm * cm * v;
                if (t > ts)      tr += mprev * cm * trans[lprev * CC + l];
            }
            lprev = l; mprev = cm;
            cyt0 = nyt0; cyt1 = nyt1; cyp0 = nyp0; cyp1 = nyp1; cm = nm;
        }
        if (lane == 0) atomicAdd(&out[rb], -(em + tr));
        return;
    }

    // ========================= in-register scan =========================
    const int g  = blockIdx.x;
    const int bq = lane & 15;
    const int q  = lane >> 4;

    // A-frags: Af[nt][kt] = E^T tile with row perm sigma.
    // sigma(nt, m) = 32*(nt&3) + 8*(m>>2) + 4*(nt>>2) + (m&3), m = lane&15.
    short8 Af[8][4];
    #pragma unroll
    for (int nt = 0; nt < 8; ++nt) {
        const int j = 32 * (nt & 3) + 8 * (bq >> 2) + 4 * (nt >> 2) + (bq & 3);
        #pragma unroll
        for (int kt = 0; kt < 4; ++kt) {
            #pragma unroll
            for (int e = 0; e < 8; ++e) {
                const int i = kt * 32 + q * 8 + e;
                Af[nt][kt][e] = (short)f2bf(__expf(trans[i * CC + j]));
            }
        }
    }

    const float4* wsg = ws + (size_t)g * (TT * 8 * 64) + lane;
    const float* yaddr[8];
    {
        const float* ybase = y_pred + (size_t)(g * 16 + bq) * TT * CC;
        #pragma unroll
        for (int c = 0; c < 8; ++c)
            yaddr[c] = ybase + ((c >> 1) * 32 + q * 8 + (c & 1) * 4);
    }
    const float* mrow = mask + (size_t)(g * 16 + bq) * TT;

    auto loadE = [&](int t, float4 (&buf)[8]) {
        #pragma unroll
        for (int c = 0; c < 8; ++c)
            buf[c] = USE_WS ? wsg[((size_t)t * 8 + c) * 64]
                            : *(const float4*)(yaddr[c] + (size_t)t * CC);
    };
    auto getE = [&](const float4& raw, float mv) -> float4 {
        if (USE_WS) return raw;
        float4 r;
        r.x = __expf(raw.x * mv); r.y = __expf(raw.y * mv);
        r.z = __expf(raw.z * mv); r.w = __expf(raw.w * mv);
        return r;
    };

    float pend = 1.f, lacc = 0.f;
    unsigned ps[16];           // packed bf16 state = next-step B-fragments
    float4 eb0[8], eb1[8];
    float mb0, mb1;

    // t=0 init: S0 = e(t=0)
    loadE(0, eb0); mb0 = mrow[0];
    #pragma unroll
    for (int c = 0; c < 8; ++c) {
        float4 e0 = getE(eb0[c], mb0);
        const int kt = c >> 1, h = c & 1;
        ps[kt * 4 + 2 * h + 0] = pkbf16(e0.x, e0.y);
        ps[kt * 4 + 2 * h + 1] = pkbf16(e0.z, e0.w);
    }
    loadE(1, eb1); mb1 = mrow[1];

#define DOSTEP(CUR, NXT, MCUR, MNXT, T, AP, RN)                                   \
    do {                                                                          \
        short8 Bf[4];                                                             \
        _Pragma("unroll")                                                         \
        for (int kt = 0; kt < 4; ++kt) {                                          \
            union { unsigned u[4]; short8 s; } bu;                                \
            bu.u[0] = ps[kt * 4 + 0]; bu.u[1] = ps[kt * 4 + 1];                   \
            bu.u[2] = ps[kt * 4 + 2]; bu.u[3] = ps[kt * 4 + 3];                   \
            Bf[kt] = bu.s;                                                        \
        }                                                                         \
        f32x4 acc[8];                                                             \
        _Pragma("unroll")                                                         \
        for (int nt = 0; nt < 8; ++nt) {                                          \
            f32x4 a = {0.f, 0.f, 0.f, 0.f};                                       \
            a = __builtin_amdgcn_mfma_f32_16x16x32_bf16(Af[nt][0], Bf[0], a, 0, 0, 0); \
            a = __builtin_amdgcn_mfma_f32_16x16x32_bf16(Af[nt][1], Bf[1], a, 0, 0, 0); \
            a = __builtin_amdgcn_mfma_f32_16x16x32_bf16(Af[nt][2], Bf[2], a, 0, 0, 0); \
            a = __builtin_amdgcn_mfma_f32_16x16x32_bf16(Af[nt][3], Bf[3], a, 0, 0, 0); \
            acc[nt] = a;                                                          \
        }                                                                         \
        const float mv = MCUR;                                                    \
        if ((T) < TT - 1) { loadE((T) + 1, NXT); MNXT = mrow[(T) + 1]; }          \
        float val[8][4];                                                          \
        _Pragma("unroll")                                                         \
        for (int nt = 0; nt < 8; ++nt) {                                          \
            const int c = 2 * (nt & 3) + (nt >> 2);                               \
            float4 e = getE(CUR[c], mv);                                          \
            val[nt][0] = acc[nt][0] * e.x; val[nt][1] = acc[nt][1] * e.y;         \
            val[nt][2] = acc[nt][2] * e.z; val[nt][3] = acc[nt][3] * e.w;         \
            if (AP) {                                                             \
                val[nt][0] *= pend; val[nt][1] *= pend;                           \
                val[nt][2] *= pend; val[nt][3] *= pend;                           \
            }                                                                     \
        }                                                                         \
        unsigned nps[16];                                                         \
        _Pragma("unroll")                                                         \
        for (int nt = 0; nt < 8; ++nt) {                                          \
            const int kt = nt & 3, h = nt >> 2;                                   \
            nps[kt * 4 + 2 * h + 0] = pkbf16(val[nt][0], val[nt][1]);             \
            nps[kt * 4 + 2 * h + 1] = pkbf16(val[nt][2], val[nt][3]);             \
        }                                                                         \
        if (__ballot(mv <= 0.f)) {                                                \
            _Pragma("unroll")                                                     \
            for (int p = 0; p < 16; ++p) {                                        \
                unsigned kept = pkbf16(lo16f(ps[p]) * pend, hi16f(ps[p]) * pend); \
                nps[p] = (mv <= 0.f) ? kept : nps[p];                             \
            }                                                                     \
        }                                                                         \
        _Pragma("unroll")                                                         \
        for (int p = 0; p < 16; ++p) ps[p] = nps[p];                              \
        if (AP) pend = 1.f;                                                       \
        if (RN) {                                                                 \
            float s  = lo16f(ps[0]);                                              \
            float bc = __shfl(s, bq, 64);                                         \
            pend = __builtin_amdgcn_rcpf(bc);                                     \
            lacc += __logf(bc);                                                   \
        }                                                                         \
    } while (0)

    for (int k = 0; k < 127; ++k) {
        const int t0 = 4 * k + 1;
        DOSTEP(eb1, eb0, mb1, mb0, t0,     true,  false);
        DOSTEP(eb0, eb1, mb0, mb1, t0 + 1, false, false);
        DOSTEP(eb1, eb0, mb1, mb0, t0 + 2, false, false);
        DOSTEP(eb0, eb1, mb0, mb1, t0 + 3, false, true);
    }
    DOSTEP(eb1, eb0, mb1, mb0, 509, true,  false);
    DOSTEP(eb0, eb1, mb0, mb1, 510, false, false);

    // -------- final step t = 511 (cur = eb1): sum instead of pack --------
    {
        short8 Bf[4];
        #pragma unroll
        for (int kt = 0; kt < 4; ++kt) {
            union { unsigned u[4]; short8 s; } bu;
            bu.u[0] = ps[kt * 4 + 0]; bu.u[1] = ps[kt * 4 + 1];
            bu.u[2] = ps[kt * 4 + 2]; bu.u[3] = ps[kt * 4 + 3];
            Bf[kt] = bu.s;
        }
        float ssum = 0.f;
        const float mv = mb1;
        #pragma unroll
        for (int nt = 0; nt < 8; ++nt) {
            f32x4 a = {0.f, 0.f, 0.f, 0.f};
            a = __builtin_amdgcn_mfma_f32_16x16x32_bf16(Af[nt][0], Bf[0], a, 0, 0, 0);
            a = __builtin_amdgcn_mfma_f32_16x16x32_bf16(Af[nt][1], Bf[1], a, 0, 0, 0);
            a = __builtin_amdgcn_mfma_f32_16x16x32_bf16(Af[nt][2], Bf[2], a, 0, 0, 0);
            a = __builtin_amdgcn_mfma_f32_16x16x32_bf16(Af[nt][3], Bf[3], a, 0, 0, 0);
            const int c = 2 * (nt & 3) + (nt >> 2);
            float4 e = getE(eb1[c], mv);
            ssum += a[0] * e.x + a[1] * e.y + a[2] * e.z + a[3] * e.w;
        }
        if (__ballot(mv <= 0.f)) {
            float os = 0.f;
            #pragma unroll
            for (int p = 0; p < 16; ++p) os += lo16f(ps[p]) + hi16f(ps[p]);
            ssum = (mv <= 0.f) ? os : ssum;   // pend == 1 here (511 % 4 == 3)
        }
        ssum += __shfl_xor(ssum, 16, 64);
        ssum += __shfl_xor(ssum, 32, 64);
        if (lane < 16) atomicAdd(&out[g * 16 + lane], __logf(ssum) + lacc);
    }
#undef DOSTEP
}

// ---------------------------------------------------------------------------
extern "C" void kernel_launch(void* const* d_in, const int* in_sizes, int n_in,
                              void* d_out, int out_size, void* d_ws, size_t ws_size,
                              hipStream_t stream) {
    (void)in_sizes; (void)n_in; (void)out_size;
    const float* y_true = (const float*)d_in[0];
    const float* y_pred = (const float*)d_in[1];
    const float* mask   = (const float*)d_in[2];
    const float* trans  = (const float*)d_in[3];
    float* out = (float*)d_out;

    const size_t need = (size_t)BB * TT * CC * sizeof(float);   // 32 MB
    hipMemsetAsync(out, 0, BB * sizeof(float), stream);
    if (ws_size >= need) {
        crf_prep<<<8192, 256, 0, stream>>>(y_pred, mask, (float4*)d_ws);
        crf_fused<true><<<8 + BB * 8, 64, 0, stream>>>(
            y_true, y_pred, mask, trans, (const float4*)d_ws, out);
    } else {
        crf_fused<false><<<8 + BB * 8, 64, 0, stream>>>(
            y_true, y_pred, mask, trans, (const float4*)d_ws, out);
    }
}